// Round 17
// baseline (103.795 us; speedup 1.0000x reference)
//
#include <hip/hip_runtime.h>
#include <math.h>

#define BB 4
#define DL 150
#define PL 1000
#define CD 64
#define NC1 40
#define NC2 80
#define NC3 160
#define L1O 997
#define L2O 990
#define L3O 979
#define L3P 980
#define DLP 152
#define PLP 984
#define JP 992
#define NINF (-1e30f)

typedef __attribute__((ext_vector_type(8))) short bf16x8;
typedef __attribute__((ext_vector_type(4))) float f32x4;

__device__ __forceinline__ float relu_(float x){ return fmaxf(x, 0.f); }
__device__ __forceinline__ float lrelu_(float x){ return x > 0.f ? x : 0.01f * x; }

__device__ __forceinline__ unsigned fenc(float x){
  unsigned u = __float_as_uint(x);
  return (u & 0x80000000u) ? ~u : (u | 0x80000000u);
}
__device__ __forceinline__ float fdec(unsigned u){
  return __uint_as_float((u & 0x80000000u) ? (u & 0x7fffffffu) : ~u);
}
__device__ __forceinline__ unsigned short bf16_(float x){
  unsigned u = __float_as_uint(x);
  unsigned r = (u + 0x7FFFu + ((u >> 16) & 1u)) >> 16;
  return (unsigned short)r;
}

// wave computes D[16co x 16j] = Wb[co][K=160] x Xb[j][K=160]^T (bf16, K-contig rows)
__device__ __forceinline__ f32x4 mfma_k160(const unsigned short* __restrict__ Wb,
                                           const unsigned short* __restrict__ Xb,
                                           int co0, int j0, int lane){
  int col = lane & 15, g = lane >> 4;
  f32x4 acc = {0.f, 0.f, 0.f, 0.f};
  const unsigned short* wr = Wb + (size_t)(co0 + col) * 160 + g * 8;
  const unsigned short* xr = Xb + (size_t)(j0 + col) * 160 + g * 8;
  #pragma unroll
  for (int k0 = 0; k0 < 5; k0++){
    bf16x8 av = *(const bf16x8*)(wr + k0 * 32);
    bf16x8 bv = *(const bf16x8*)(xr + k0 * 32);
    acc = __builtin_amdgcn_mfma_f32_16x16x32_bf16(av, bv, acc, 0, 0, 0);
  }
  return acc;
}

// ---- fused prep casts + conv1 ----
// blocks: [0,720) w3r | [720,820) Wpb | [820,920) Wattb | [920,1020) Wdb
//         [1020,1180) w2r | [1180,1580) drugb | [1580,2080) conv1 (local proj)
__global__ __launch_bounds__(256) void k_pc1(const float* __restrict__ emb,
                       const float* __restrict__ w1,
                       const float* __restrict__ w3, unsigned short* __restrict__ w3r,
                       const float* __restrict__ Wp, unsigned short* __restrict__ Wpb,
                       const float* __restrict__ Watt, unsigned short* __restrict__ Wattb,
                       const float* __restrict__ Wd, unsigned short* __restrict__ Wdb,
                       const float* __restrict__ w2, unsigned short* __restrict__ w2r,
                       const float* __restrict__ drug, unsigned short* __restrict__ drugb,
                       const int* __restrict__ prot, const float* __restrict__ b1,
                       unsigned short* __restrict__ h1bT){
  int blk = blockIdx.x;
  int tid = threadIdx.x;
  if (blk < 720){
    int e = blk * 256 + tid;                    // [kk12][co160][ci96]
    int kk = e / (160 * 96); int r = e % (160 * 96);
    int co = r / 96, ci = r % 96;
    float v = (ci < NC2) ? w3[(size_t)co * 960 + ci * 12 + kk] : 0.f;
    w3r[e] = bf16_(v);
    return;
  }
  if (blk < 820){ int e = (blk - 720) * 256 + tid; Wpb[e]   = bf16_(Wp[e]);   return; }
  if (blk < 920){ int e = (blk - 820) * 256 + tid; Wattb[e] = bf16_(Watt[e]); return; }
  if (blk < 1020){ int e = (blk - 920) * 256 + tid; Wdb[e]  = bf16_(Wd[e]);   return; }
  if (blk < 1180){
    int e = (blk - 1020) * 256 + tid;           // [kk8][co80][ci64]
    int kk = e / (80 * 64); int r = e % (80 * 64);
    int co = r / 64, ci = r % 64;
    float v = (ci < NC1) ? w2[(size_t)(co * NC1 + ci) * 8 + kk] : 0.f;
    w2r[e] = bf16_(v);
    return;
  }
  if (blk < 1580){
    int e = (blk - 1180) * 256 + tid;           // [b][i160][c160]
    int b = e / 25600; int r = e % 25600;
    int i = r / 160, c = r % 160;
    float v = (i < DL) ? drug[((size_t)b * DL + i) * 160 + c] : 0.f;
    drugb[e] = bf16_(v);
    return;
  }
  // ---- conv1 with block-local proj, COALESCED staging ----
  __shared__ float sp[26 * 161];                // 16.7 KB proj table
  __shared__ float embl[26 * CD];               // 6.7 KB
  __shared__ float w1t[CD * 164];               // 42.0 KB, [ci][k*40+co]
  int cb = blk - 1580;
  int b = cb / 125;
  int t2 = (cb % 125) * 256 + tid;
  for (int i = tid; i < 26 * CD; i += 256) embl[i] = emb[i];
  for (int i = tid; i < NC1 * CD * 4; i += 256){
    int co = i >> 8, r = i & 255;               // w1 linear: [co][ci][k]
    int ci = r >> 2, k = r & 3;
    w1t[ci * 164 + k * 40 + co] = w1[i];
  }
  __syncthreads();
  for (int e = tid; e < 26 * 160; e += 256){
    int tok = e / 160, rem = e % 160, k = rem / 40, co = rem % 40;
    float a = 0.f;
    const float* er = &embl[tok * CD];
    const float* wrr = &w1t[k * 40 + co];
    #pragma unroll 8
    for (int ci = 0; ci < CD; ci++) a = fmaf(er[ci], wrr[ci * 164], a);
    sp[tok * 161 + k * 40 + co] = a;
  }
  __syncthreads();
  int ci = (t2 & 31) * 2, p = t2 >> 5;
  float v0 = 0.f, v1 = 0.f;
  if (p < L1O && ci < NC1){
    const int* pr = prot + b * PL + p;
    int t0 = pr[0], t1 = pr[1], t2b = pr[2], t3 = pr[3];
    v0 = relu_(b1[ci] + sp[t0 * 161 + ci] + sp[t1 * 161 + 40 + ci]
             + sp[t2b * 161 + 80 + ci] + sp[t3 * 161 + 120 + ci]);
    int c1 = ci + 1;
    v1 = relu_(b1[c1] + sp[t0 * 161 + c1] + sp[t1 * 161 + 40 + c1]
             + sp[t2b * 161 + 80 + c1] + sp[t3 * 161 + 120 + c1]);
  }
  ushort2 o; o.x = bf16_(v0); o.y = bf16_(v1);
  *(ushort2*)(&h1bT[((size_t)b * 1000 + p) * 64 + ci]) = o;
}

// ---- conv2 via MFMA: grid 320 = b4 x cog5 x pt16(64p); writes relu'd bf16 h2bT ----
__global__ __launch_bounds__(256) void k_c2m(const unsigned short* __restrict__ h1bT,
                        const unsigned short* __restrict__ w2r,
                        const float* __restrict__ bias,
                        unsigned short* __restrict__ h2bT){
  int blk = blockIdx.x;
  int pt = blk % 16; int t = blk / 16;
  int cog = t % 5; int b = t / 5;
  int co0 = cog * 16;
  int wave = threadIdx.x >> 6, lane = threadIdx.x & 63;
  int col = lane & 15, g = lane >> 4;
  int p0 = pt * 64 + wave * 16;
  if (p0 >= JP) return;
  f32x4 acc = {0.f, 0.f, 0.f, 0.f};
  const unsigned short* wbase = w2r + (size_t)(co0 + col) * 64 + g * 8;
  const unsigned short* xbase = h1bT + (size_t)b * 1000 * 64 + g * 8;
  int prow = p0 + col;
  #pragma unroll 2
  for (int kk = 0; kk < 8; kk++){
    int rp = prow + kk; if (rp > 999) rp = 999;
    const unsigned short* xr = xbase + (size_t)rp * 64;
    const unsigned short* wr = wbase + (size_t)kk * (80 * 64);
    #pragma unroll
    for (int ks = 0; ks < 2; ks++){
      bf16x8 av = *(const bf16x8*)(wr + ks * 32);
      bf16x8 bv = *(const bf16x8*)(xr + ks * 32);
      acc = __builtin_amdgcn_mfma_f32_16x16x32_bf16(av, bv, acc, 0, 0, 0);
    }
  }
  int p = p0 + col;
  if (p < JP){
    unsigned short tb[4];
    bool live = p < L2O;
    #pragma unroll
    for (int r = 0; r < 4; r++){
      int co = co0 + g * 4 + r;
      tb[r] = live ? bf16_(relu_(acc[r] + bias[co])) : (unsigned short)0;
    }
    *(uint2*)(&h2bT[((size_t)b * JP + p) * 96 + co0 + g * 4]) = *(uint2*)tb;
    if (cog == 4){
      uint2 z = {0u, 0u};
      *(uint2*)(&h2bT[((size_t)b * JP + p) * 96 + 80 + g * 4]) = z;
    }
  }
}

// ---- conv3 via MFMA; emits f32 pconv + relu'd bf16 pconvTb[b][p][co] ----
__global__ __launch_bounds__(256) void k_c3m(const unsigned short* __restrict__ h2bT,
                        const unsigned short* __restrict__ w3r,
                        const float* __restrict__ bias, float* __restrict__ pconv,
                        unsigned short* __restrict__ pconvTb){
  int blk = blockIdx.x;
  int pt = blk % 16; int t = blk / 16;
  int cog = t % 10; int b = t / 10;
  int co0 = cog * 16;
  int wave = threadIdx.x >> 6, lane = threadIdx.x & 63;
  int col = lane & 15, g = lane >> 4;
  int p0 = pt * 64 + wave * 16;
  f32x4 acc = {0.f, 0.f, 0.f, 0.f};
  const unsigned short* wbase = w3r + (size_t)(co0 + col) * 96 + g * 8;
  const unsigned short* xbase = h2bT + (size_t)b * JP * 96 + g * 8;
  int prow = p0 + col;
  for (int kk = 0; kk < 12; kk++){
    int rp = prow + kk; if (rp > 991) rp = 991;
    const unsigned short* xr = xbase + (size_t)rp * 96;
    const unsigned short* wr = wbase + (size_t)kk * (160 * 96);
    #pragma unroll
    for (int ks = 0; ks < 3; ks++){
      bf16x8 av = *(const bf16x8*)(wr + ks * 32);
      bf16x8 bv = *(const bf16x8*)(xr + ks * 32);
      acc = __builtin_amdgcn_mfma_f32_16x16x32_bf16(av, bv, acc, 0, 0, 0);
    }
  }
  if (p0 >= L3O) return;
  int p = p0 + col;
  if (p < L3O){
    unsigned short tb[4];
    #pragma unroll
    for (int r = 0; r < 4; r++){
      int co = co0 + g * 4 + r;
      float v = acc[r] + bias[co];
      pconv[(size_t)(b * NC3 + co) * L3P + p] = v;
      tb[r] = bf16_(relu_(v));
    }
    *(uint2*)(&pconvTb[((size_t)b * JP + p) * 160 + co0 + g * 4]) = *(uint2*)tb;
  }
}

// ---- pattm: blocks 0..39 drug-att MFMA (+enc init); 40..287 protein-att MFMA ----
__global__ __launch_bounds__(256) void k_pattm(const unsigned short* __restrict__ drugb,
                        const int* __restrict__ natoms,
                        const unsigned short* __restrict__ Wdb,
                        const float* __restrict__ bd,
                        float* __restrict__ dattT, unsigned* __restrict__ enc,
                        const unsigned short* __restrict__ pconvTb,
                        const int* __restrict__ prot,
                        const unsigned short* __restrict__ Wpb,
                        const float* __restrict__ bp, float* __restrict__ pattT){
  int blk = blockIdx.x;
  int tid = threadIdx.x;
  int wave = tid >> 6, lane = tid & 63;
  int col = lane & 15, g = lane >> 4;
  if (blk < 40){
    if (blk == 0){
      for (int k = tid; k < 2 * BB * NC3; k += 256) enc[k] = 0u;
    }
    int b = blk / 10, it = blk % 10;
    int i0 = it * 16;
    const unsigned short* Xb = drugb + (size_t)b * 160 * 160;
    for (int ct = wave; ct < 10; ct += 4){
      int co0 = ct * 16;
      f32x4 acc = mfma_k160(Wdb, Xb, co0, i0, lane);
      int i = i0 + col;
      if (i < DL){
        bool act = i < natoms[b];
        #pragma unroll
        for (int r = 0; r < 4; r++){
          int co = co0 + g * 4 + r;
          dattT[(size_t)(b * NC3 + co) * DLP + i] = act ? (acc[r] + bd[co]) : 0.f;
        }
      }
    }
    return;
  }
  int q = blk - 40;
  int jt = q % 62, b = q / 62;
  int j0 = jt * 16;
  const unsigned short* Xb = pconvTb + (size_t)b * JP * 160;
  for (int ct = wave; ct < 10; ct += 4){
    int co0 = ct * 16;
    f32x4 acc = mfma_k160(Wpb, Xb, co0, j0, lane);
    int j = j0 + col;
    if (j < L3O){
      bool act = prot[b * PL + j] > 0;
      #pragma unroll
      for (int r = 0; r < 4; r++){
        int co = co0 + g * 4 + r;
        pattT[(size_t)(b * NC3 + co) * PLP + j] = act ? (acc[r] + bp[co]) : 0.f;
      }
    }
  }
}

// ---- means: emits cmeanTb bf16 [b][160][160] and pmeanTb bf16 [b][992][160] ----
__global__ __launch_bounds__(256) void k_means(const float* __restrict__ dattT,
                        const float* __restrict__ pattT,
                        unsigned short* __restrict__ cmeanTb,
                        unsigned short* __restrict__ pmeanTb){
  __shared__ __align__(16) float sda[DLP];
  __shared__ __align__(16) float spa[PLP];
  __shared__ float scm[4][DLP];
  int b = blockIdx.x / NC3, c = blockIdx.x % NC3;
  int tid = threadIdx.x;
  const float4* dr = (const float4*)(dattT + (size_t)(b * NC3 + c) * DLP);
  const float4* pr = (const float4*)(pattT + (size_t)(b * NC3 + c) * PLP);
  if (tid < DLP / 4) *(float4*)(&sda[tid * 4]) = dr[tid];
  if (tid < PLP / 4) *(float4*)(&spa[tid * 4]) = pr[tid];
  __syncthreads();
  for (int t = tid; t < 600; t += 256){
    int i = t >> 2, qq = t & 3;
    int js = qq * 244;
    int je = (qq == 3) ? L3O : js + 244;
    float v = sda[i];
    float s0 = 0.f, s1 = 0.f, s2 = 0.f, s3 = 0.f;
    const float4* p4 = (const float4*)(spa + js);
    int n4 = (je - js) >> 2;
    for (int u = 0; u < n4; u++){
      float4 p = p4[u];
      s0 += relu_(v + p.x); s1 += relu_(v + p.y);
      s2 += relu_(v + p.z); s3 += relu_(v + p.w);
    }
    for (int j = js + n4 * 4; j < je; j++) s0 += relu_(v + spa[j]);
    scm[qq][i] = (s0 + s1) + (s2 + s3);
  }
  for (int j = tid; j < L3O; j += 256){
    float v = spa[j];
    float s0 = 0.f, s1 = 0.f, s2 = 0.f, s3 = 0.f;
    const float4* d4 = (const float4*)sda;
    #pragma unroll 4
    for (int u = 0; u < 37; u++){
      float4 d = d4[u];
      s0 += relu_(v + d.x); s1 += relu_(v + d.y);
      s2 += relu_(v + d.z); s3 += relu_(v + d.w);
    }
    s0 += relu_(v + sda[148]); s1 += relu_(v + sda[149]);
    float pm = ((s0 + s1) + (s2 + s3)) * (1.f / DL);
    pmeanTb[((size_t)b * JP + j) * 160 + c] = bf16_(pm);
  }
  __syncthreads();
  if (tid < 160){
    float s = 0.f;
    if (tid < DL)
      s = ((scm[0][tid] + scm[1][tid]) + (scm[2][tid] + scm[3][tid])) * (1.f / L3O);
    cmeanTb[((size_t)b * 160 + tid) * 160 + c] = bf16_(s);
  }
}

// ---- attem: blocks 0..39 compound gate MFMA; 40..287 protein gate MFMA ----
__global__ __launch_bounds__(256) void k_attem(const unsigned short* __restrict__ cmeanTb,
                        const unsigned short* __restrict__ pmeanTb,
                        const unsigned short* __restrict__ Wattb,
                        const float* __restrict__ batt,
                        const float* __restrict__ drug,
                        const float* __restrict__ pconv, unsigned* __restrict__ enc){
  int blk = blockIdx.x;
  int tid = threadIdx.x;
  int wave = tid >> 6, lane = tid & 63;
  int col = lane & 15, g = lane >> 4;
  if (blk < 40){
    int b = blk / 10, cot = blk % 10;
    int co0 = cot * 16;
    const unsigned short* Xb = cmeanTb + (size_t)b * 160 * 160;
    float m[4];
    #pragma unroll
    for (int r = 0; r < 4; r++) m[r] = NINF;
    for (int it = wave; it < 10; it += 4){
      int i0 = it * 16;
      f32x4 acc = mfma_k160(Wattb, Xb, co0, i0, lane);
      int i = i0 + col;
      if (i < DL){
        #pragma unroll
        for (int r = 0; r < 4; r++){
          int co = co0 + g * 4 + r;
          float gate = 1.f / (1.f + expf(-(acc[r] + batt[co])));
          float val = drug[((size_t)b * DL + i) * 160 + co] * (0.5f + gate);
          m[r] = fmaxf(m[r], val);
        }
      }
    }
    #pragma unroll
    for (int r = 0; r < 4; r++){
      #pragma unroll
      for (int off = 1; off < 16; off <<= 1)
        m[r] = fmaxf(m[r], __shfl_xor(m[r], off, 64));
    }
    if (col == 0){
      #pragma unroll
      for (int r = 0; r < 4; r++)
        atomicMax(&enc[b * NC3 + co0 + g * 4 + r], fenc(m[r]));
    }
    return;
  }
  int q = blk - 40;
  int jt = q % 62, b = q / 62;
  int j0 = jt * 16;
  const unsigned short* Xb = pmeanTb + (size_t)b * JP * 160;
  for (int ct = wave; ct < 10; ct += 4){
    int co0 = ct * 16;
    f32x4 acc = mfma_k160(Wattb, Xb, co0, j0, lane);
    int j = j0 + col;
    float m[4];
    #pragma unroll
    for (int r = 0; r < 4; r++){
      int co = co0 + g * 4 + r;
      if (j < L3O){
        float gate = 1.f / (1.f + expf(-(acc[r] + batt[co])));
        float pv = relu_(pconv[(size_t)(b * NC3 + co) * L3P + j]);
        m[r] = pv * (0.5f + gate);
      } else m[r] = NINF;
    }
    #pragma unroll
    for (int r = 0; r < 4; r++){
      #pragma unroll
      for (int off = 1; off < 16; off <<= 1)
        m[r] = fmaxf(m[r], __shfl_xor(m[r], off, 64));
    }
    if (col == 0){
      #pragma unroll
      for (int r = 0; r < 4; r++)
        atomicMax(&enc[BB * NC3 + b * NC3 + co0 + g * 4 + r], fenc(m[r]));
    }
  }
}

// ---- MLP 1: 320 -> 1024 ----
__global__ __launch_bounds__(256) void k_mlp1(const unsigned* __restrict__ enc,
                        const float* __restrict__ W1, const float* __restrict__ bf1,
                        float* __restrict__ f1){
  int b = blockIdx.x >> 6, og = blockIdx.x & 63;
  int o = og * 16 + (threadIdx.x >> 4);
  int q = threadIdx.x & 15;
  const float4* wr = (const float4*)(W1 + (size_t)o * 320);
  float4 a = make_float4(0.f, 0.f, 0.f, 0.f);
  #pragma unroll
  for (int mi = 0; mi < 5; mi++){
    int k4 = q + mi * 16;
    int k = k4 * 4;
    const unsigned* e = (k < 160) ? (enc + b * NC3 + k)
                                  : (enc + BB * NC3 + b * NC3 + (k - 160));
    float4 wv = wr[k4];
    a.x = fmaf(fdec(e[0]), wv.x, a.x);
    a.y = fmaf(fdec(e[1]), wv.y, a.y);
    a.z = fmaf(fdec(e[2]), wv.z, a.z);
    a.w = fmaf(fdec(e[3]), wv.w, a.w);
  }
  float r = a.x + a.y + a.z + a.w;
  r += __shfl_xor(r, 1, 64); r += __shfl_xor(r, 2, 64);
  r += __shfl_xor(r, 4, 64); r += __shfl_xor(r, 8, 64);
  if (q == 0) f1[b * 1024 + o] = lrelu_(r + bf1[o]);
}

// ---- MLP 2: 1024 -> 1024 ----
__global__ __launch_bounds__(256) void k_mlp2(const float* __restrict__ x,
                        const float* __restrict__ W, const float* __restrict__ bias,
                        float* __restrict__ y){
  int b = blockIdx.x >> 6, og = blockIdx.x & 63;
  int o = og * 16 + (threadIdx.x >> 4);
  int q = threadIdx.x & 15;
  const float4* wr = (const float4*)(W + (size_t)o * 1024);
  const float4* xr = (const float4*)(x + b * 1024);
  float4 a = make_float4(0.f, 0.f, 0.f, 0.f);
  #pragma unroll
  for (int mi = 0; mi < 16; mi++){
    int k4 = q + mi * 16;
    float4 wv = wr[k4], xv = xr[k4];
    a.x = fmaf(xv.x, wv.x, a.x);
    a.y = fmaf(xv.y, wv.y, a.y);
    a.z = fmaf(xv.z, wv.z, a.z);
    a.w = fmaf(xv.w, wv.w, a.w);
  }
  float r = a.x + a.y + a.z + a.w;
  r += __shfl_xor(r, 1, 64); r += __shfl_xor(r, 2, 64);
  r += __shfl_xor(r, 4, 64); r += __shfl_xor(r, 8, 64);
  if (q == 0) y[b * 1024 + o] = lrelu_(r + bias[o]);
}

// ---- MLP 3: 1024 -> 512 ----
__global__ __launch_bounds__(256) void k_mlp3(const float* __restrict__ x,
                        const float* __restrict__ W, const float* __restrict__ bias,
                        float* __restrict__ y){
  int b = blockIdx.x >> 5, og = blockIdx.x & 31;
  int o = og * 16 + (threadIdx.x >> 4);
  int q = threadIdx.x & 15;
  const float4* wr = (const float4*)(W + (size_t)o * 1024);
  const float4* xr = (const float4*)(x + b * 1024);
  float4 a = make_float4(0.f, 0.f, 0.f, 0.f);
  #pragma unroll
  for (int mi = 0; mi < 16; mi++){
    int k4 = q + mi * 16;
    float4 wv = wr[k4], xv = xr[k4];
    a.x = fmaf(xv.x, wv.x, a.x);
    a.y = fmaf(xv.y, wv.y, a.y);
    a.z = fmaf(xv.z, wv.z, a.z);
    a.w = fmaf(xv.w, wv.w, a.w);
  }
  float r = a.x + a.y + a.z + a.w;
  r += __shfl_xor(r, 1, 64); r += __shfl_xor(r, 2, 64);
  r += __shfl_xor(r, 4, 64); r += __shfl_xor(r, 8, 64);
  if (q == 0) y[b * 512 + o] = lrelu_(r + bias[o]);
}

// ---- MLP out: 512 -> 2 ----
__global__ void k_mlp4(const float* __restrict__ f3, const float* __restrict__ Wo,
                       const float* __restrict__ bo, float* __restrict__ out){
  int tid = threadIdx.x;
  int g = tid >> 5, lane = tid & 31;
  int b = g >> 1, o = g & 1;
  const float4* xr = (const float4*)(f3 + b * 512);
  const float4* wr = (const float4*)(Wo + o * 512);
  float4 a = make_float4(0.f, 0.f, 0.f, 0.f);
  #pragma unroll
  for (int mI = 0; mI < 4; mI++){
    int k4 = lane + mI * 32;
    float4 xv = xr[k4], wv = wr[k4];
    a.x = fmaf(xv.x, wv.x, a.x);
    a.y = fmaf(xv.y, wv.y, a.y);
    a.z = fmaf(xv.z, wv.z, a.z);
    a.w = fmaf(xv.w, wv.w, a.w);
  }
  float r = a.x + a.y + a.z + a.w;
  for (int off = 16; off; off >>= 1) r += __shfl_xor(r, off, 64);
  if (lane == 0) out[b * 2 + o] = r + bo[o];
}

extern "C" void kernel_launch(void* const* d_in, const int* in_sizes, int n_in,
                              void* d_out, int out_size, void* d_ws, size_t ws_size,
                              hipStream_t stream) {
  const float* drug  = (const float*)d_in[0];
  const int*   natoms= (const int*)d_in[1];
  const int*   prot  = (const int*)d_in[2];
  const float* emb   = (const float*)d_in[3];
  const float* w1    = (const float*)d_in[4];
  const float* b1    = (const float*)d_in[5];
  const float* w2    = (const float*)d_in[6];
  const float* b2    = (const float*)d_in[7];
  const float* w3    = (const float*)d_in[8];
  const float* b3    = (const float*)d_in[9];
  const float* Wd    = (const float*)d_in[10];
  const float* bd    = (const float*)d_in[11];
  const float* Wp    = (const float*)d_in[12];
  const float* bp    = (const float*)d_in[13];
  const float* Watt  = (const float*)d_in[14];
  const float* batt  = (const float*)d_in[15];
  const float* W1    = (const float*)d_in[16];
  const float* bf1   = (const float*)d_in[17];
  const float* W2    = (const float*)d_in[18];
  const float* bf2   = (const float*)d_in[19];
  const float* W3    = (const float*)d_in[20];
  const float* bf3   = (const float*)d_in[21];
  const float* Wo    = (const float*)d_in[22];
  const float* bo    = (const float*)d_in[23];
  float* out = (float*)d_out;

  float* ws = (float*)d_ws;
  float* f1     = ws;                        // 4096
  float* f2     = ws + 4096;                 // 4096
  float* f3     = ws + 8192;                 // 2048
  float* dattT  = ws + 10240;                // 97280
  float* pattT  = ws + 107520;               // 629760
  float* pconv  = ws + 737280;               // 627200
  unsigned* enc = (unsigned*)(ws + 1364480); // 1280 u32
  unsigned short* h1bT    = (unsigned short*)(ws + 1369088); // 256000 bf16
  unsigned short* w2r     = (unsigned short*)(ws + 1497088); // 40960 bf16
  unsigned short* h2bT    = (unsigned short*)(ws + 1517568); // 380928 bf16
  unsigned short* w3r     = (unsigned short*)(ws + 1708032); // 184320 bf16
  unsigned short* pconvTb = (unsigned short*)(ws + 1800192); // 634880 bf16
  unsigned short* pmeanTb = (unsigned short*)(ws + 2117632); // 634880 bf16
  unsigned short* cmeanTb = (unsigned short*)(ws + 2435072); // 102400 bf16
  unsigned short* drugb   = (unsigned short*)(ws + 2486272); // 102400 bf16
  unsigned short* Wpb     = (unsigned short*)(ws + 2537472); // 25600 bf16
  unsigned short* Wattb   = (unsigned short*)(ws + 2550272); // 25600 bf16
  unsigned short* Wdb     = (unsigned short*)(ws + 2563072); // 25600 bf16

  k_pc1   <<<2080, 256, 0, stream>>>(emb, w1, w3, w3r, Wp, Wpb, Watt, Wattb,
                                     Wd, Wdb, w2, w2r, drug, drugb,
                                     prot, b1, h1bT);
  k_c2m   <<<320, 256, 0, stream>>>(h1bT, w2r, b2, h2bT);
  k_c3m   <<<640, 256, 0, stream>>>(h2bT, w3r, b3, pconv, pconvTb);
  k_pattm <<<288, 256, 0, stream>>>(drugb, natoms, Wdb, bd, dattT, enc,
                                    pconvTb, prot, Wpb, bp, pattT);
  k_means <<<BB * NC3, 256, 0, stream>>>(dattT, pattT, cmeanTb, pmeanTb);
  k_attem <<<288, 256, 0, stream>>>(cmeanTb, pmeanTb, Wattb, batt, drug,
                                    pconv, enc);
  k_mlp1  <<<256, 256, 0, stream>>>(enc, W1, bf1, f1);
  k_mlp2  <<<256, 256, 0, stream>>>(f1, W2, bf2, f2);
  k_mlp3  <<<128, 256, 0, stream>>>(f2, W3, bf3, f3);
  k_mlp4  <<<1, 256, 0, stream>>>(f3, Wo, bo, out);
}

// Round 18
// 98.175 us; speedup vs baseline: 1.0572x; 1.0572x over previous
//
#include <hip/hip_runtime.h>
#include <math.h>

#define BB 4
#define DL 150
#define PL 1000
#define CD 64
#define NC1 40
#define NC2 80
#define NC3 160
#define L1O 997
#define L2O 990
#define L3O 979
#define L3P 980
#define DLP 152
#define PLP 984
#define JP 992
#define NINF (-1e30f)

typedef __attribute__((ext_vector_type(8))) short bf16x8;
typedef __attribute__((ext_vector_type(4))) float f32x4;

__device__ __forceinline__ float relu_(float x){ return fmaxf(x, 0.f); }
__device__ __forceinline__ float lrelu_(float x){ return x > 0.f ? x : 0.01f * x; }

__device__ __forceinline__ unsigned fenc(float x){
  unsigned u = __float_as_uint(x);
  return (u & 0x80000000u) ? ~u : (u | 0x80000000u);
}
__device__ __forceinline__ float fdec(unsigned u){
  return __uint_as_float((u & 0x80000000u) ? (u & 0x7fffffffu) : ~u);
}
__device__ __forceinline__ unsigned short bf16_(float x){
  unsigned u = __float_as_uint(x);
  unsigned r = (u + 0x7FFFu + ((u >> 16) & 1u)) >> 16;
  return (unsigned short)r;
}

// wave computes D[16co x 16j] = Wb[co][K=160] x Xb[j][K=160]^T (bf16, K-contig rows)
__device__ __forceinline__ f32x4 mfma_k160(const unsigned short* __restrict__ Wb,
                                           const unsigned short* __restrict__ Xb,
                                           int co0, int j0, int lane){
  int col = lane & 15, g = lane >> 4;
  f32x4 acc = {0.f, 0.f, 0.f, 0.f};
  const unsigned short* wr = Wb + (size_t)(co0 + col) * 160 + g * 8;
  const unsigned short* xr = Xb + (size_t)(j0 + col) * 160 + g * 8;
  #pragma unroll
  for (int k0 = 0; k0 < 5; k0++){
    bf16x8 av = *(const bf16x8*)(wr + k0 * 32);
    bf16x8 bv = *(const bf16x8*)(xr + k0 * 32);
    acc = __builtin_amdgcn_mfma_f32_16x16x32_bf16(av, bv, acc, 0, 0, 0);
  }
  return acc;
}

// ---- prep: proj | w3r | Wpb | Wattb | Wdb | w2r | drugb ----
__global__ __launch_bounds__(256) void k_prep(const float* __restrict__ emb,
                       const float* __restrict__ w1, float* __restrict__ projG,
                       const float* __restrict__ w3, unsigned short* __restrict__ w3r,
                       const float* __restrict__ Wp, unsigned short* __restrict__ Wpb,
                       const float* __restrict__ Watt, unsigned short* __restrict__ Wattb,
                       const float* __restrict__ Wd, unsigned short* __restrict__ Wdb,
                       const float* __restrict__ w2, unsigned short* __restrict__ w2r,
                       const float* __restrict__ drug, unsigned short* __restrict__ drugb){
  int blk = blockIdx.x;
  if (blk < 17){
    int e = blk * 256 + threadIdx.x;
    if (e >= 26 * 160) return;
    int tok = e / 160, rem = e % 160, k = rem / 40, co = rem % 40;
    float a = 0.f;
    const float* er = emb + tok * CD;
    const float* wr = w1 + co * (CD * 4) + k;
    #pragma unroll 8
    for (int ci = 0; ci < CD; ci++) a = fmaf(er[ci], wr[ci * 4], a);
    projG[tok * 161 + k * 40 + co] = a;
    return;
  }
  if (blk < 737){
    int e = (blk - 17) * 256 + threadIdx.x;
    int kk = e / (160 * 96); int r = e % (160 * 96);
    int co = r / 96, ci = r % 96;
    float v = (ci < NC2) ? w3[(size_t)co * 960 + ci * 12 + kk] : 0.f;
    w3r[e] = bf16_(v);
    return;
  }
  if (blk < 837){
    int e = (blk - 737) * 256 + threadIdx.x;
    Wpb[e] = bf16_(Wp[e]);
    return;
  }
  if (blk < 937){
    int e = (blk - 837) * 256 + threadIdx.x;
    Wattb[e] = bf16_(Watt[e]);
    return;
  }
  if (blk < 1037){
    int e = (blk - 937) * 256 + threadIdx.x;
    Wdb[e] = bf16_(Wd[e]);
    return;
  }
  if (blk < 1197){
    int e = (blk - 1037) * 256 + threadIdx.x;   // [kk8][co80][ci64]
    int kk = e / (80 * 64); int r = e % (80 * 64);
    int co = r / 64, ci = r % 64;
    float v = (ci < NC1) ? w2[(size_t)(co * NC1 + ci) * 8 + kk] : 0.f;
    w2r[e] = bf16_(v);
    return;
  }
  {
    int e = (blk - 1197) * 256 + threadIdx.x;   // [b][i160][c160]
    int b = e / 25600; int r = e % 25600;
    int i = r / 160, c = r % 160;
    float v = (i < DL) ? drug[((size_t)b * DL + i) * 160 + c] : 0.f;
    drugb[e] = bf16_(v);
  }
}

// ---- conv1: embed+K4 conv, writes relu'd bf16 h1bT[b][1000][64] (ci/p padded) ----
__global__ __launch_bounds__(256) void k_conv1(const int* __restrict__ prot,
                        const float* __restrict__ projG, const float* __restrict__ b1,
                        unsigned short* __restrict__ h1bT){
  __shared__ float sp[26 * 161];
  int b = blockIdx.x / 125;
  int t = (blockIdx.x % 125) * 256 + threadIdx.x;   // 0..31999
  for (int k = threadIdx.x; k < 26 * 161; k += 256) sp[k] = projG[k];
  __syncthreads();
  int ci = (t & 31) * 2, p = t >> 5;                // p 0..999
  float v0 = 0.f, v1 = 0.f;
  if (p < L1O && ci < NC1){
    const int* pr = prot + b * PL + p;
    int t0 = pr[0], t1 = pr[1], t2 = pr[2], t3 = pr[3];
    v0 = relu_(b1[ci] + sp[t0 * 161 + ci] + sp[t1 * 161 + 40 + ci]
             + sp[t2 * 161 + 80 + ci] + sp[t3 * 161 + 120 + ci]);
    int c1 = ci + 1;
    v1 = relu_(b1[c1] + sp[t0 * 161 + c1] + sp[t1 * 161 + 40 + c1]
             + sp[t2 * 161 + 80 + c1] + sp[t3 * 161 + 120 + c1]);
  }
  ushort2 o; o.x = bf16_(v0); o.y = bf16_(v1);
  *(ushort2*)(&h1bT[((size_t)b * 1000 + p) * 64 + ci]) = o;
}

// ---- conv2 via MFMA: grid 320 = b4 x cog5 x pt16(64p); writes relu'd bf16 h2bT ----
__global__ __launch_bounds__(256) void k_c2m(const unsigned short* __restrict__ h1bT,
                        const unsigned short* __restrict__ w2r,
                        const float* __restrict__ bias,
                        unsigned short* __restrict__ h2bT){
  int blk = blockIdx.x;
  int pt = blk % 16; int t = blk / 16;
  int cog = t % 5; int b = t / 5;
  int co0 = cog * 16;
  int wave = threadIdx.x >> 6, lane = threadIdx.x & 63;
  int col = lane & 15, g = lane >> 4;
  int p0 = pt * 64 + wave * 16;
  if (p0 >= JP) return;
  f32x4 acc = {0.f, 0.f, 0.f, 0.f};
  const unsigned short* wbase = w2r + (size_t)(co0 + col) * 64 + g * 8;
  const unsigned short* xbase = h1bT + (size_t)b * 1000 * 64 + g * 8;
  int prow = p0 + col;
  #pragma unroll 2
  for (int kk = 0; kk < 8; kk++){
    int rp = prow + kk; if (rp > 999) rp = 999;
    const unsigned short* xr = xbase + (size_t)rp * 64;
    const unsigned short* wr = wbase + (size_t)kk * (80 * 64);
    #pragma unroll
    for (int ks = 0; ks < 2; ks++){
      bf16x8 av = *(const bf16x8*)(wr + ks * 32);
      bf16x8 bv = *(const bf16x8*)(xr + ks * 32);
      acc = __builtin_amdgcn_mfma_f32_16x16x32_bf16(av, bv, acc, 0, 0, 0);
    }
  }
  int p = p0 + col;
  if (p < JP){
    unsigned short tb[4];
    bool live = p < L2O;
    #pragma unroll
    for (int r = 0; r < 4; r++){
      int co = co0 + g * 4 + r;
      tb[r] = live ? bf16_(relu_(acc[r] + bias[co])) : (unsigned short)0;
    }
    *(uint2*)(&h2bT[((size_t)b * JP + p) * 96 + co0 + g * 4]) = *(uint2*)tb;
    if (cog == 4){
      uint2 z = {0u, 0u};
      *(uint2*)(&h2bT[((size_t)b * JP + p) * 96 + 80 + g * 4]) = z;
    }
  }
}

// ---- conv3 via MFMA; emits f32 pconv + relu'd bf16 pconvTb[b][p][co] ----
__global__ __launch_bounds__(256) void k_c3m(const unsigned short* __restrict__ h2bT,
                        const unsigned short* __restrict__ w3r,
                        const float* __restrict__ bias, float* __restrict__ pconv,
                        unsigned short* __restrict__ pconvTb){
  int blk = blockIdx.x;
  int pt = blk % 16; int t = blk / 16;
  int cog = t % 10; int b = t / 10;
  int co0 = cog * 16;
  int wave = threadIdx.x >> 6, lane = threadIdx.x & 63;
  int col = lane & 15, g = lane >> 4;
  int p0 = pt * 64 + wave * 16;
  f32x4 acc = {0.f, 0.f, 0.f, 0.f};
  const unsigned short* wbase = w3r + (size_t)(co0 + col) * 96 + g * 8;
  const unsigned short* xbase = h2bT + (size_t)b * JP * 96 + g * 8;
  int prow = p0 + col;
  for (int kk = 0; kk < 12; kk++){
    int rp = prow + kk; if (rp > 991) rp = 991;
    const unsigned short* xr = xbase + (size_t)rp * 96;
    const unsigned short* wr = wbase + (size_t)kk * (160 * 96);
    #pragma unroll
    for (int ks = 0; ks < 3; ks++){
      bf16x8 av = *(const bf16x8*)(wr + ks * 32);
      bf16x8 bv = *(const bf16x8*)(xr + ks * 32);
      acc = __builtin_amdgcn_mfma_f32_16x16x32_bf16(av, bv, acc, 0, 0, 0);
    }
  }
  if (p0 >= L3O) return;
  int p = p0 + col;
  if (p < L3O){
    unsigned short tb[4];
    #pragma unroll
    for (int r = 0; r < 4; r++){
      int co = co0 + g * 4 + r;
      float v = acc[r] + bias[co];
      pconv[(size_t)(b * NC3 + co) * L3P + p] = v;
      tb[r] = bf16_(relu_(v));
    }
    *(uint2*)(&pconvTb[((size_t)b * JP + p) * 160 + co0 + g * 4]) = *(uint2*)tb;
  }
}

// ---- pattm: blocks 0..39 drug-att MFMA (+enc init); 40..287 protein-att MFMA ----
__global__ __launch_bounds__(256) void k_pattm(const unsigned short* __restrict__ drugb,
                        const int* __restrict__ natoms,
                        const unsigned short* __restrict__ Wdb,
                        const float* __restrict__ bd,
                        float* __restrict__ dattT, unsigned* __restrict__ enc,
                        const unsigned short* __restrict__ pconvTb,
                        const int* __restrict__ prot,
                        const unsigned short* __restrict__ Wpb,
                        const float* __restrict__ bp, float* __restrict__ pattT){
  int blk = blockIdx.x;
  int tid = threadIdx.x;
  int wave = tid >> 6, lane = tid & 63;
  int col = lane & 15, g = lane >> 4;
  if (blk < 40){
    if (blk == 0){
      for (int k = tid; k < 2 * BB * NC3; k += 256) enc[k] = 0u;
    }
    int b = blk / 10, it = blk % 10;
    int i0 = it * 16;
    const unsigned short* Xb = drugb + (size_t)b * 160 * 160;
    for (int ct = wave; ct < 10; ct += 4){
      int co0 = ct * 16;
      f32x4 acc = mfma_k160(Wdb, Xb, co0, i0, lane);
      int i = i0 + col;
      if (i < DL){
        bool act = i < natoms[b];
        #pragma unroll
        for (int r = 0; r < 4; r++){
          int co = co0 + g * 4 + r;
          dattT[(size_t)(b * NC3 + co) * DLP + i] = act ? (acc[r] + bd[co]) : 0.f;
        }
      }
    }
    return;
  }
  int q = blk - 40;
  int jt = q % 62, b = q / 62;
  int j0 = jt * 16;
  const unsigned short* Xb = pconvTb + (size_t)b * JP * 160;
  for (int ct = wave; ct < 10; ct += 4){
    int co0 = ct * 16;
    f32x4 acc = mfma_k160(Wpb, Xb, co0, j0, lane);
    int j = j0 + col;
    if (j < L3O){
      bool act = prot[b * PL + j] > 0;
      #pragma unroll
      for (int r = 0; r < 4; r++){
        int co = co0 + g * 4 + r;
        pattT[(size_t)(b * NC3 + co) * PLP + j] = act ? (acc[r] + bp[co]) : 0.f;
      }
    }
  }
}

// ---- means: emits cmeanTb bf16 [b][160][160] and pmeanTb bf16 [b][992][160] ----
__global__ __launch_bounds__(256) void k_means(const float* __restrict__ dattT,
                        const float* __restrict__ pattT,
                        unsigned short* __restrict__ cmeanTb,
                        unsigned short* __restrict__ pmeanTb){
  __shared__ __align__(16) float sda[DLP];
  __shared__ __align__(16) float spa[PLP];
  __shared__ float scm[4][DLP];
  int b = blockIdx.x / NC3, c = blockIdx.x % NC3;
  int tid = threadIdx.x;
  const float4* dr = (const float4*)(dattT + (size_t)(b * NC3 + c) * DLP);
  const float4* pr = (const float4*)(pattT + (size_t)(b * NC3 + c) * PLP);
  if (tid < DLP / 4) *(float4*)(&sda[tid * 4]) = dr[tid];
  if (tid < PLP / 4) *(float4*)(&spa[tid * 4]) = pr[tid];
  __syncthreads();
  for (int t = tid; t < 600; t += 256){
    int i = t >> 2, qq = t & 3;
    int js = qq * 244;
    int je = (qq == 3) ? L3O : js + 244;
    float v = sda[i];
    float s0 = 0.f, s1 = 0.f, s2 = 0.f, s3 = 0.f;
    const float4* p4 = (const float4*)(spa + js);
    int n4 = (je - js) >> 2;
    for (int u = 0; u < n4; u++){
      float4 p = p4[u];
      s0 += relu_(v + p.x); s1 += relu_(v + p.y);
      s2 += relu_(v + p.z); s3 += relu_(v + p.w);
    }
    for (int j = js + n4 * 4; j < je; j++) s0 += relu_(v + spa[j]);
    scm[qq][i] = (s0 + s1) + (s2 + s3);
  }
  for (int j = tid; j < L3O; j += 256){
    float v = spa[j];
    float s0 = 0.f, s1 = 0.f, s2 = 0.f, s3 = 0.f;
    const float4* d4 = (const float4*)sda;
    #pragma unroll 4
    for (int u = 0; u < 37; u++){
      float4 d = d4[u];
      s0 += relu_(v + d.x); s1 += relu_(v + d.y);
      s2 += relu_(v + d.z); s3 += relu_(v + d.w);
    }
    s0 += relu_(v + sda[148]); s1 += relu_(v + sda[149]);
    float pm = ((s0 + s1) + (s2 + s3)) * (1.f / DL);
    pmeanTb[((size_t)b * JP + j) * 160 + c] = bf16_(pm);
  }
  __syncthreads();
  if (tid < 160){
    float s = 0.f;
    if (tid < DL)
      s = ((scm[0][tid] + scm[1][tid]) + (scm[2][tid] + scm[3][tid])) * (1.f / L3O);
    cmeanTb[((size_t)b * 160 + tid) * 160 + c] = bf16_(s);
  }
}

// ---- attem: blocks 0..39 compound gate MFMA; 40..287 protein gate MFMA ----
__global__ __launch_bounds__(256) void k_attem(const unsigned short* __restrict__ cmeanTb,
                        const unsigned short* __restrict__ pmeanTb,
                        const unsigned short* __restrict__ Wattb,
                        const float* __restrict__ batt,
                        const float* __restrict__ drug,
                        const float* __restrict__ pconv, unsigned* __restrict__ enc){
  int blk = blockIdx.x;
  int tid = threadIdx.x;
  int wave = tid >> 6, lane = tid & 63;
  int col = lane & 15, g = lane >> 4;
  if (blk < 40){
    int b = blk / 10, cot = blk % 10;
    int co0 = cot * 16;
    const unsigned short* Xb = cmeanTb + (size_t)b * 160 * 160;
    float m[4];
    #pragma unroll
    for (int r = 0; r < 4; r++) m[r] = NINF;
    for (int it = wave; it < 10; it += 4){
      int i0 = it * 16;
      f32x4 acc = mfma_k160(Wattb, Xb, co0, i0, lane);
      int i = i0 + col;
      if (i < DL){
        #pragma unroll
        for (int r = 0; r < 4; r++){
          int co = co0 + g * 4 + r;
          float gate = 1.f / (1.f + expf(-(acc[r] + batt[co])));
          float val = drug[((size_t)b * DL + i) * 160 + co] * (0.5f + gate);
          m[r] = fmaxf(m[r], val);
        }
      }
    }
    #pragma unroll
    for (int r = 0; r < 4; r++){
      #pragma unroll
      for (int off = 1; off < 16; off <<= 1)
        m[r] = fmaxf(m[r], __shfl_xor(m[r], off, 64));
    }
    if (col == 0){
      #pragma unroll
      for (int r = 0; r < 4; r++)
        atomicMax(&enc[b * NC3 + co0 + g * 4 + r], fenc(m[r]));
    }
    return;
  }
  int q = blk - 40;
  int jt = q % 62, b = q / 62;
  int j0 = jt * 16;
  const unsigned short* Xb = pmeanTb + (size_t)b * JP * 160;
  for (int ct = wave; ct < 10; ct += 4){
    int co0 = ct * 16;
    f32x4 acc = mfma_k160(Wattb, Xb, co0, j0, lane);
    int j = j0 + col;
    float m[4];
    #pragma unroll
    for (int r = 0; r < 4; r++){
      int co = co0 + g * 4 + r;
      if (j < L3O){
        float gate = 1.f / (1.f + expf(-(acc[r] + batt[co])));
        float pv = relu_(pconv[(size_t)(b * NC3 + co) * L3P + j]);
        m[r] = pv * (0.5f + gate);
      } else m[r] = NINF;
    }
    #pragma unroll
    for (int r = 0; r < 4; r++){
      #pragma unroll
      for (int off = 1; off < 16; off <<= 1)
        m[r] = fmaxf(m[r], __shfl_xor(m[r], off, 64));
    }
    if (col == 0){
      #pragma unroll
      for (int r = 0; r < 4; r++)
        atomicMax(&enc[BB * NC3 + b * NC3 + co0 + g * 4 + r], fenc(m[r]));
    }
  }
}

// ---- MLP 1: 320 -> 1024 ----
__global__ __launch_bounds__(256) void k_mlp1(const unsigned* __restrict__ enc,
                        const float* __restrict__ W1, const float* __restrict__ bf1,
                        float* __restrict__ f1){
  int b = blockIdx.x >> 6, og = blockIdx.x & 63;
  int o = og * 16 + (threadIdx.x >> 4);
  int q = threadIdx.x & 15;
  const float4* wr = (const float4*)(W1 + (size_t)o * 320);
  float4 a = make_float4(0.f, 0.f, 0.f, 0.f);
  #pragma unroll
  for (int mi = 0; mi < 5; mi++){
    int k4 = q + mi * 16;
    int k = k4 * 4;
    const unsigned* e = (k < 160) ? (enc + b * NC3 + k)
                                  : (enc + BB * NC3 + b * NC3 + (k - 160));
    float4 wv = wr[k4];
    a.x = fmaf(fdec(e[0]), wv.x, a.x);
    a.y = fmaf(fdec(e[1]), wv.y, a.y);
    a.z = fmaf(fdec(e[2]), wv.z, a.z);
    a.w = fmaf(fdec(e[3]), wv.w, a.w);
  }
  float r = a.x + a.y + a.z + a.w;
  r += __shfl_xor(r, 1, 64); r += __shfl_xor(r, 2, 64);
  r += __shfl_xor(r, 4, 64); r += __shfl_xor(r, 8, 64);
  if (q == 0) f1[b * 1024 + o] = lrelu_(r + bf1[o]);
}

// ---- MLP 2: 1024 -> 1024 ----
__global__ __launch_bounds__(256) void k_mlp2(const float* __restrict__ x,
                        const float* __restrict__ W, const float* __restrict__ bias,
                        float* __restrict__ y){
  int b = blockIdx.x >> 6, og = blockIdx.x & 63;
  int o = og * 16 + (threadIdx.x >> 4);
  int q = threadIdx.x & 15;
  const float4* wr = (const float4*)(W + (size_t)o * 1024);
  const float4* xr = (const float4*)(x + b * 1024);
  float4 a = make_float4(0.f, 0.f, 0.f, 0.f);
  #pragma unroll
  for (int mi = 0; mi < 16; mi++){
    int k4 = q + mi * 16;
    float4 wv = wr[k4], xv = xr[k4];
    a.x = fmaf(xv.x, wv.x, a.x);
    a.y = fmaf(xv.y, wv.y, a.y);
    a.z = fmaf(xv.z, wv.z, a.z);
    a.w = fmaf(xv.w, wv.w, a.w);
  }
  float r = a.x + a.y + a.z + a.w;
  r += __shfl_xor(r, 1, 64); r += __shfl_xor(r, 2, 64);
  r += __shfl_xor(r, 4, 64); r += __shfl_xor(r, 8, 64);
  if (q == 0) y[b * 1024 + o] = lrelu_(r + bias[o]);
}

// ---- MLP 3: 1024 -> 512 ----
__global__ __launch_bounds__(256) void k_mlp3(const float* __restrict__ x,
                        const float* __restrict__ W, const float* __restrict__ bias,
                        float* __restrict__ y){
  int b = blockIdx.x >> 5, og = blockIdx.x & 31;
  int o = og * 16 + (threadIdx.x >> 4);
  int q = threadIdx.x & 15;
  const float4* wr = (const float4*)(W + (size_t)o * 1024);
  const float4* xr = (const float4*)(x + b * 1024);
  float4 a = make_float4(0.f, 0.f, 0.f, 0.f);
  #pragma unroll
  for (int mi = 0; mi < 16; mi++){
    int k4 = q + mi * 16;
    float4 wv = wr[k4], xv = xr[k4];
    a.x = fmaf(xv.x, wv.x, a.x);
    a.y = fmaf(xv.y, wv.y, a.y);
    a.z = fmaf(xv.z, wv.z, a.z);
    a.w = fmaf(xv.w, wv.w, a.w);
  }
  float r = a.x + a.y + a.z + a.w;
  r += __shfl_xor(r, 1, 64); r += __shfl_xor(r, 2, 64);
  r += __shfl_xor(r, 4, 64); r += __shfl_xor(r, 8, 64);
  if (q == 0) y[b * 512 + o] = lrelu_(r + bias[o]);
}

// ---- MLP out: 512 -> 2 ----
__global__ void k_mlp4(const float* __restrict__ f3, const float* __restrict__ Wo,
                       const float* __restrict__ bo, float* __restrict__ out){
  int tid = threadIdx.x;
  int g = tid >> 5, lane = tid & 31;
  int b = g >> 1, o = g & 1;
  const float4* xr = (const float4*)(f3 + b * 512);
  const float4* wr = (const float4*)(Wo + o * 512);
  float4 a = make_float4(0.f, 0.f, 0.f, 0.f);
  #pragma unroll
  for (int mI = 0; mI < 4; mI++){
    int k4 = lane + mI * 32;
    float4 xv = xr[k4], wv = wr[k4];
    a.x = fmaf(xv.x, wv.x, a.x);
    a.y = fmaf(xv.y, wv.y, a.y);
    a.z = fmaf(xv.z, wv.z, a.z);
    a.w = fmaf(xv.w, wv.w, a.w);
  }
  float r = a.x + a.y + a.z + a.w;
  for (int off = 16; off; off >>= 1) r += __shfl_xor(r, off, 64);
  if (lane == 0) out[b * 2 + o] = r + bo[o];
}

extern "C" void kernel_launch(void* const* d_in, const int* in_sizes, int n_in,
                              void* d_out, int out_size, void* d_ws, size_t ws_size,
                              hipStream_t stream) {
  const float* drug  = (const float*)d_in[0];
  const int*   natoms= (const int*)d_in[1];
  const int*   prot  = (const int*)d_in[2];
  const float* emb   = (const float*)d_in[3];
  const float* w1    = (const float*)d_in[4];
  const float* b1    = (const float*)d_in[5];
  const float* w2    = (const float*)d_in[6];
  const float* b2    = (const float*)d_in[7];
  const float* w3    = (const float*)d_in[8];
  const float* b3    = (const float*)d_in[9];
  const float* Wd    = (const float*)d_in[10];
  const float* bd    = (const float*)d_in[11];
  const float* Wp    = (const float*)d_in[12];
  const float* bp    = (const float*)d_in[13];
  const float* Watt  = (const float*)d_in[14];
  const float* batt  = (const float*)d_in[15];
  const float* W1    = (const float*)d_in[16];
  const float* bf1   = (const float*)d_in[17];
  const float* W2    = (const float*)d_in[18];
  const float* bf2   = (const float*)d_in[19];
  const float* W3    = (const float*)d_in[20];
  const float* bf3   = (const float*)d_in[21];
  const float* Wo    = (const float*)d_in[22];
  const float* bo    = (const float*)d_in[23];
  float* out = (float*)d_out;

  float* ws = (float*)d_ws;
  float* f1     = ws;                        // 4096
  float* f2     = ws + 4096;                 // 4096
  float* f3     = ws + 8192;                 // 2048
  float* dattT  = ws + 10240;                // 97280
  float* pattT  = ws + 107520;               // 629760
  float* pconv  = ws + 737280;               // 627200
  unsigned* enc = (unsigned*)(ws + 1364480); // 1280 u32
  float* projG  = ws + 1364864;              // 4186
  unsigned short* h1bT    = (unsigned short*)(ws + 1369088); // 256000 bf16
  unsigned short* w2r     = (unsigned short*)(ws + 1497088); // 40960 bf16
  unsigned short* h2bT    = (unsigned short*)(ws + 1517568); // 380928 bf16
  unsigned short* w3r     = (unsigned short*)(ws + 1708032); // 184320 bf16
  unsigned short* pconvTb = (unsigned short*)(ws + 1800192); // 634880 bf16
  unsigned short* pmeanTb = (unsigned short*)(ws + 2117632); // 634880 bf16
  unsigned short* cmeanTb = (unsigned short*)(ws + 2435072); // 102400 bf16
  unsigned short* drugb   = (unsigned short*)(ws + 2486272); // 102400 bf16
  unsigned short* Wpb     = (unsigned short*)(ws + 2537472); // 25600 bf16
  unsigned short* Wattb   = (unsigned short*)(ws + 2550272); // 25600 bf16
  unsigned short* Wdb     = (unsigned short*)(ws + 2563072); // 25600 bf16

  k_prep  <<<1597, 256, 0, stream>>>(emb, w1, projG, w3, w3r, Wp, Wpb,
                                     Watt, Wattb, Wd, Wdb, w2, w2r, drug, drugb);
  k_conv1 <<<500, 256, 0, stream>>>(prot, projG, b1, h1bT);
  k_c2m   <<<320, 256, 0, stream>>>(h1bT, w2r, b2, h2bT);
  k_c3m   <<<640, 256, 0, stream>>>(h2bT, w3r, b3, pconv, pconvTb);
  k_pattm <<<288, 256, 0, stream>>>(drugb, natoms, Wdb, bd, dattT, enc,
                                    pconvTb, prot, Wpb, bp, pattT);
  k_means <<<BB * NC3, 256, 0, stream>>>(dattT, pattT, cmeanTb, pmeanTb);
  k_attem <<<288, 256, 0, stream>>>(cmeanTb, pmeanTb, Wattb, batt, drug,
                                    pconv, enc);
  k_mlp1  <<<256, 256, 0, stream>>>(enc, W1, bf1, f1);
  k_mlp2  <<<256, 256, 0, stream>>>(f1, W2, bf2, f2);
  k_mlp3  <<<128, 256, 0, stream>>>(f2, W3, bf3, f3);
  k_mlp4  <<<1, 256, 0, stream>>>(f3, Wo, bo, out);
}